// Round 1
// baseline (948.974 us; speedup 1.0000x reference)
//
#include <hip/hip_runtime.h>
#include <hip/hip_bf16.h>
#include <math.h>
#include <cstdint>

#define KDIM 4096   // IN_FEATURES
#define ODIM 4096   // OUT_FEATURES
#define MDIM 8192   // N_ROWS
#define EPSF 1e-6f
#define TM05 2047.5f   // threshold(=2048) - 0.5

typedef __bf16 bf16x8 __attribute__((ext_vector_type(8)));
typedef float f32x4 __attribute__((ext_vector_type(4)));
typedef unsigned short u16;

// element deltas inside workspace (buffers laid out contiguously)
#define XY_DELTA (MDIM * KDIM)   // Xb -> Yb   (in u16 elements)
#define CD_DELTA (ODIM * KDIM)   // Cb -> C2b  (in u16 elements)

// var LDS exchange buffer: col-major, stride 132 u16 per column
#define VSTRIDE 132

// ---- fused GEMM geometry ----
// block tile: mu 128x256 + var 128x256, BK=32, 8 waves (4 mu + 4 var, 2x2 each)
#define BM 128
#define BN 256
#define BK 32
#define NT (KDIM / BK)          // 128 k-tiles
// LDS: 3 buffers x 48KB = 144KB (1 block/CU), 2-tiles-ahead pipeline
#define BUF_BYTES 49152
#define LX_OFF 0                // 128x32 bf16 = 8KB
#define LY_OFF 8192
#define LC_OFF 16384            // 256x32 bf16 = 16KB
#define LD_OFF 32768

__device__ __forceinline__ u16 f2bf(float f) {
  __hip_bfloat16 h = __float2bfloat16(f);
  return __builtin_bit_cast(u16, h);
}
__device__ __forceinline__ float bf2f(u16 b) {
  unsigned int u = ((unsigned int)b) << 16;
  return __builtin_bit_cast(float, u);
}

// async global->LDS direct copy, 16 B per lane (dst must be lane-linear).
__device__ __forceinline__ void async_cp16(void* lds, const void* g) {
  __builtin_amdgcn_global_load_lds(
      (__attribute__((address_space(1))) void*)(uintptr_t)g,
      (__attribute__((address_space(3))) void*)lds, 16, 0, 0);
}

// ---------------- prep: X -> bf16 X, bf16 Y = x*(1-x) ----------------
__global__ void prep_x_kernel(const float4* __restrict__ x4,
                              ushort4* __restrict__ Xb,
                              ushort4* __restrict__ Yb) {
  int i = blockIdx.x * blockDim.x + threadIdx.x;
  float4 v = x4[i];
  ushort4 xo, yo;
  xo.x = f2bf(v.x); xo.y = f2bf(v.y); xo.z = f2bf(v.z); xo.w = f2bf(v.w);
  yo.x = f2bf(v.x * (1.0f - v.x));
  yo.y = f2bf(v.y * (1.0f - v.y));
  yo.z = f2bf(v.z * (1.0f - v.z));
  yo.w = f2bf(v.w * (1.0f - v.w));
  Xb[i] = xo;
  Yb[i] = yo;
}

// ---------------- prep: W -> bf16 C=2*sig(w)-1, bf16 C2=C*C, sums ----------------
__device__ __forceinline__ void wcomp(float w, u16& cb, u16& c2b, float& sd, float& sde) {
  float pw = 1.0f / (1.0f + __expf(-w));
  float c  = 2.0f * pw - 1.0f;
  float d  = 1.0f - pw;
  cb  = f2bf(c);
  c2b = f2bf(c * c);
  sd  += d;
  sde += d * pw;
}

__global__ void prep_w_kernel(const float4* __restrict__ w4,
                              ushort4* __restrict__ Cb,
                              ushort4* __restrict__ C2b,
                              float* __restrict__ sumd,
                              float* __restrict__ sumde) {
  const int o = blockIdx.x;
  const int t = threadIdx.x;
  const float4* wr = w4 + (size_t)o * (KDIM / 4);
  ushort4* cr  = Cb  + (size_t)o * (KDIM / 4);
  ushort4* c2r = C2b + (size_t)o * (KDIM / 4);
  float sd = 0.f, sde = 0.f;
#pragma unroll
  for (int it = 0; it < KDIM / 4 / 256; ++it) {
    int k4 = t + it * 256;
    float4 w = wr[k4];
    ushort4 co, c2o;
    wcomp(w.x, co.x, c2o.x, sd, sde);
    wcomp(w.y, co.y, c2o.y, sd, sde);
    wcomp(w.z, co.z, c2o.z, sd, sde);
    wcomp(w.w, co.w, c2o.w, sd, sde);
    cr[k4]  = co;
    c2r[k4] = c2o;
  }
#pragma unroll
  for (int off = 32; off > 0; off >>= 1) {
    sd  += __shfl_down(sd, off);
    sde += __shfl_down(sde, off);
  }
  __shared__ float red[8];
  if ((t & 63) == 0) { red[t >> 6] = sd; red[4 + (t >> 6)] = sde; }
  __syncthreads();
  if (t == 0) {
    sumd[o]  = red[0] + red[1] + red[2] + red[3];
    sumde[o] = red[4] + red[5] + red[6] + red[7];
  }
}

// ---------------- fused dual-GEMM, 3-buffer counted-vmcnt pipeline ----------------
// 512 threads = 8 waves. Waves 0-3: mu = X@C^T; waves 4-7: var = Y@C2^T.
// Each wave: 64 rows x 128 cols of its 128x256 tile (acc[4][8]).
// LDS tile layout (per operand tile): row-pair units of 128B = 8 chunks of 16B;
// chunk c of unit u holds global chunk g = c ^ (u&7), where g = (row&1)*4 + kchunk.
// -> ds_read_b128 fragments land 2 lanes/bank (free); global src stays coalesced.
// Schedule per k-tile: 2 phases of {ds_read || 3x global_load_lds (tile t+2) ->
// s_barrier -> lgkmcnt(0) -> setprio(1) 16 MFMA setprio(0)}; vmcnt(6) once per
// tile before the trailing barrier (never drains to 0 until the last 2 tiles).
__global__ __launch_bounds__(512, 2) void gemm_fused_kernel(
    const u16* __restrict__ Xb, const u16* __restrict__ Cb,
    const float* __restrict__ sumd, const float* __restrict__ sumde,
    float* __restrict__ out) {
  __shared__ __attribute__((aligned(128))) char smem[3 * BUF_BYTES];

  const int tid  = threadIdx.x;
  const int lane = tid & 63;
  const int wave = tid >> 6;       // 0..7
  const int grp  = wave >> 2;      // 0 = mu, 1 = var
  const int sub  = wave & 3;
  const int wr   = sub >> 1;       // row half (64 rows each)
  const int wc   = sub & 1;        // col half (128 cols each)
  const int quad = lane >> 4;
  const int r16  = lane & 15;

  // XCD-chunked swizzle: each XCD gets 128 consecutive wgids = 2 N-panels x all M
  const int raw = blockIdx.x;
  const int wg  = (raw & 7) * 128 + (raw >> 3);
  const int n0  = (wg >> 6) * BN;     // 16 N-panels
  const int m0  = (wg & 63) * BM;     // 64 M-panels

  // staging source map (per 8KB round = 128 rows x 64B): thread t -> unit u=t>>3,
  // chunk c=t&7, g=c^(u&7) -> global row 2u+(g>>2), elems (g&3)*8
  const int su    = tid >> 3;
  const int sg    = (tid & 7) ^ (su & 7);
  const int srow  = 2 * su + (sg >> 2);
  const int selem = (sg & 3) * 8;

  const u16* gX = Xb + (size_t)(m0 + srow) * KDIM + selem;
  const u16* gC = Cb + (size_t)(n0 + srow) * KDIM + selem;

#define STAGE_A(sbuf, kt) do {                                              \
    char* _d = smem + (sbuf) * BUF_BYTES + tid * 16;                        \
    const u16* _px = gX + (size_t)(kt) * BK;                                \
    const u16* _pc = gC + (size_t)(kt) * BK;                                \
    async_cp16(_d + LX_OFF, _px);                                           \
    async_cp16(_d + LY_OFF, _px + XY_DELTA);                                \
    async_cp16(_d + LC_OFF, _pc);                                           \
  } while (0)
#define STAGE_B(sbuf, kt) do {                                              \
    char* _d = smem + (sbuf) * BUF_BYTES + tid * 16;                        \
    const u16* _pc = gC + (size_t)(kt) * BK;                                \
    async_cp16(_d + LC_OFF + 8192, _pc + (size_t)128 * KDIM);               \
    async_cp16(_d + LD_OFF,        _pc + CD_DELTA);                         \
    async_cp16(_d + LD_OFF + 8192, _pc + CD_DELTA + (size_t)128 * KDIM);    \
  } while (0)

  // fragment read offsets: row = base + f*16 + r16, kchunk = quad
  // unit u = base/2 + f*8 + (r16>>1); chunk = ((r16&1)*4 + quad) ^ (u&7)
  const int rh    = r16 >> 1;
  const int fbase = rh * 128 + (((((r16 & 1) << 2) + quad) ^ rh) << 4);
  const int aT = (grp ? LY_OFF : LX_OFF) + wr * 4096 + fbase;  // 64-row slice
  const int bT = (grp ? LD_OFF : LC_OFF) + wc * 8192 + fbase;  // 128-col slice

  f32x4 acc[4][8];
#pragma unroll
  for (int i = 0; i < 4; ++i)
#pragma unroll
    for (int j = 0; j < 8; ++j) acc[i][j] = f32x4{0.f, 0.f, 0.f, 0.f};

  // prologue: stage tiles 0 and 1; wait for tile 0 (tile 1's 6 loads stay in flight)
  STAGE_A(0, 0); STAGE_B(0, 0);
  STAGE_A(1, 1); STAGE_B(1, 1);
  asm volatile("s_waitcnt vmcnt(6)" ::: "memory");
  __builtin_amdgcn_s_barrier();

  int rb = 0;  // read buffer = t % 3
  for (int t = 0; t < NT; ++t) {
    const char* base = smem + rb * BUF_BYTES;
    const int sb = rb ? rb - 1 : 2;   // (t+2) % 3
    bf16x8 a[4], b[8];

    // ---- phase 0: a[0..3], b[0..3]; stage X/Y/C0 of tile t+2 ----
#pragma unroll
    for (int i = 0; i < 4; ++i) a[i] = *(const bf16x8*)(base + aT + i * 1024);
#pragma unroll
    for (int j = 0; j < 4; ++j) b[j] = *(const bf16x8*)(base + bT + j * 1024);
    if (t + 2 < NT) STAGE_A(sb, t + 2);
    __builtin_amdgcn_s_barrier();
    asm volatile("s_waitcnt lgkmcnt(0)" ::: "memory");
    __builtin_amdgcn_sched_barrier(0);
    __builtin_amdgcn_s_setprio(1);
#pragma unroll
    for (int i = 0; i < 4; ++i)
#pragma unroll
      for (int j = 0; j < 4; ++j)
        acc[i][j] = __builtin_amdgcn_mfma_f32_16x16x32_bf16(a[i], b[j], acc[i][j], 0, 0, 0);
    __builtin_amdgcn_s_setprio(0);
    __builtin_amdgcn_s_barrier();

    // ---- phase 1: b[4..7]; stage C1/D0/D1 of tile t+2 ----
#pragma unroll
    for (int j = 4; j < 8; ++j) b[j] = *(const bf16x8*)(base + bT + j * 1024);
    if (t + 2 < NT) STAGE_B(sb, t + 2);
    __builtin_amdgcn_s_barrier();
    asm volatile("s_waitcnt lgkmcnt(0)" ::: "memory");
    __builtin_amdgcn_sched_barrier(0);
    __builtin_amdgcn_s_setprio(1);
#pragma unroll
    for (int i = 0; i < 4; ++i)
#pragma unroll
      for (int j = 4; j < 8; ++j)
        acc[i][j] = __builtin_amdgcn_mfma_f32_16x16x32_bf16(a[i], b[j], acc[i][j], 0, 0, 0);
    __builtin_amdgcn_s_setprio(0);
    // tile-end wait: next tile's 6 loads done once <=6 (tile t+2's) remain.
    // last two tiles have no newer loads -> full drain (also protects epilogue LDS reuse)
    if (t < NT - 2) { asm volatile("s_waitcnt vmcnt(6)" ::: "memory"); }
    else            { asm volatile("s_waitcnt vmcnt(0)" ::: "memory"); }
    __builtin_amdgcn_s_barrier();

    rb = rb + 1 == 3 ? 0 : rb + 1;
  }

  // ---- epilogue ----
  // C/D layout: out col = wc*128 + j*16 + r16, out row = wr*64 + i*16 + quad*4 + reg
  u16* vb = (u16*)smem;
  if (grp) {
    // var waves: round to bf16, park in LDS col-major (stride VSTRIDE)
#pragma unroll
    for (int j = 0; j < 8; ++j) {
      const int cl = wc * 128 + j * 16 + r16;
#pragma unroll
      for (int i = 0; i < 4; ++i) {
        const int rl = wr * 64 + i * 16 + quad * 4;
        f32x4 v = acc[i][j];
        ushort4 p;
        p.x = f2bf(v[0]); p.y = f2bf(v[1]); p.z = f2bf(v[2]); p.w = f2bf(v[3]);
        *(ushort4*)(vb + cl * VSTRIDE + rl) = p;
      }
    }
  }
  __syncthreads();
  if (!grp) {
    const float inv_rt2 = 0.70710678118654752f;
#pragma unroll
    for (int j = 0; j < 8; ++j) {
      const int cl  = wc * 128 + j * 16 + r16;
      const int col = n0 + cl;
      const float sd  = sumd[col];
      const float sde = sumde[col] + EPSF;
#pragma unroll
      for (int i = 0; i < 4; ++i) {
        const int rl   = wr * 64 + i * 16 + quad * 4;
        const int mrow = m0 + rl;
        const ushort4 p = *(const ushort4*)(vb + cl * VSTRIDE + rl);
        f32x4 m4 = acc[i][j];
        const float vv[4] = {bf2f(p.x), bf2f(p.y), bf2f(p.z), bf2f(p.w)};
#pragma unroll
        for (int r = 0; r < 4; ++r) {
          float mu  = m4[r] + sd;
          float var = vv[r] + sde;
          float z = (TM05 - mu) * rsqrtf(var) * inv_rt2;
          out[(size_t)(mrow + r) * ODIM + col] = 0.5f * erfcf(z);
        }
      }
    }
  }
}

// ---------------- launch ----------------
// ws layout (bytes):
//   0         : Cb   (33554432)
//   33554432  : C2b  (33554432)   = Cb + CD_DELTA elems
//   67108864  : sumd (16384)
//   67125248  : sumde(16384)
//   67141632  : Xb   (67108864)
//   134250496 : Yb   (67108864)   = Xb + XY_DELTA elems
extern "C" void kernel_launch(void* const* d_in, const int* in_sizes, int n_in,
                              void* d_out, int out_size, void* d_ws, size_t ws_size,
                              hipStream_t stream) {
  const float* p_x    = (const float*)d_in[0];
  const float* weight = (const float*)d_in[1];
  float* out = (float*)d_out;
  char* ws = (char*)d_ws;

  u16* Cb      = (u16*)(ws);
  float* sumd  = (float*)(ws + 67108864);
  float* sumde = (float*)(ws + 67125248);
  u16* Xb      = (u16*)(ws + 67141632);

  prep_w_kernel<<<ODIM, 256, 0, stream>>>((const float4*)weight, (ushort4*)Cb,
                                          (ushort4*)(ws + 33554432), sumd, sumde);
  prep_x_kernel<<<(MDIM * KDIM / 4) / 256, 256, 0, stream>>>((const float4*)p_x,
                                                             (ushort4*)Xb,
                                                             (ushort4*)(ws + 134250496));
  gemm_fused_kernel<<<dim3((ODIM / BN) * (MDIM / BM)), 512, 0, stream>>>(
      Xb, Cb, sumd, sumde, out);
}

// Round 2
// 884.599 us; speedup vs baseline: 1.0728x; 1.0728x over previous
//
#include <hip/hip_runtime.h>
#include <hip/hip_bf16.h>
#include <math.h>
#include <cstdint>

#define KDIM 4096   // IN_FEATURES
#define ODIM 4096   // OUT_FEATURES
#define MDIM 8192   // N_ROWS
#define EPSF 1e-6f
#define TM05 2047.5f   // threshold(=2048) - 0.5

typedef __bf16 bf16x8 __attribute__((ext_vector_type(8)));
typedef float f32x4 __attribute__((ext_vector_type(4)));
typedef unsigned short u16;

// element deltas inside workspace (buffers laid out contiguously)
#define XY_DELTA (MDIM * KDIM)   // Xb -> Yb   (in u16 elements)
#define CD_DELTA (ODIM * KDIM)   // Cb -> C2b  (in u16 elements)

// var LDS exchange buffer: col-major, stride 132 u16 per column
#define VSTRIDE 132

// ---- fused GEMM geometry ----
// block tile: mu 128x256 + var 128x256, BK=32, 8 waves (4 mu + 4 var, 2x2 each)
#define BM 128
#define BN 256
#define BK 32
#define NT (KDIM / BK)          // 128 k-tiles
// LDS: 3 buffers x 48KB = 144KB (1 block/CU), 2-tiles-ahead pipeline
#define BUF_BYTES 49152
#define LX_OFF 0                // 128x32 bf16 = 8KB
#define LY_OFF 8192
#define LC_OFF 16384            // 256x32 bf16 = 16KB
#define LD_OFF 32768

__device__ __forceinline__ u16 f2bf(float f) {
  __hip_bfloat16 h = __float2bfloat16(f);
  return __builtin_bit_cast(u16, h);
}
__device__ __forceinline__ float bf2f(u16 b) {
  unsigned int u = ((unsigned int)b) << 16;
  return __builtin_bit_cast(float, u);
}

// async global->LDS direct copy, 16 B per lane (dst must be lane-linear).
__device__ __forceinline__ void async_cp16(void* lds, const void* g) {
  __builtin_amdgcn_global_load_lds(
      (__attribute__((address_space(1))) void*)(uintptr_t)g,
      (__attribute__((address_space(3))) void*)lds, 16, 0, 0);
}

// ---------------- prep: X -> bf16 X, bf16 Y = x*(1-x) ----------------
__global__ void prep_x_kernel(const float4* __restrict__ x4,
                              ushort4* __restrict__ Xb,
                              ushort4* __restrict__ Yb) {
  int i = blockIdx.x * blockDim.x + threadIdx.x;
  float4 v = x4[i];
  ushort4 xo, yo;
  xo.x = f2bf(v.x); xo.y = f2bf(v.y); xo.z = f2bf(v.z); xo.w = f2bf(v.w);
  yo.x = f2bf(v.x * (1.0f - v.x));
  yo.y = f2bf(v.y * (1.0f - v.y));
  yo.z = f2bf(v.z * (1.0f - v.z));
  yo.w = f2bf(v.w * (1.0f - v.w));
  Xb[i] = xo;
  Yb[i] = yo;
}

// ---------------- prep: W -> bf16 C=2*sig(w)-1, bf16 C2=C*C, sums ----------------
__device__ __forceinline__ void wcomp(float w, u16& cb, u16& c2b, float& sd, float& sde) {
  float pw = 1.0f / (1.0f + __expf(-w));
  float c  = 2.0f * pw - 1.0f;
  float d  = 1.0f - pw;
  cb  = f2bf(c);
  c2b = f2bf(c * c);
  sd  += d;
  sde += d * pw;
}

__global__ void prep_w_kernel(const float4* __restrict__ w4,
                              ushort4* __restrict__ Cb,
                              ushort4* __restrict__ C2b,
                              float* __restrict__ sumd,
                              float* __restrict__ sumde) {
  const int o = blockIdx.x;
  const int t = threadIdx.x;
  const float4* wr = w4 + (size_t)o * (KDIM / 4);
  ushort4* cr  = Cb  + (size_t)o * (KDIM / 4);
  ushort4* c2r = C2b + (size_t)o * (KDIM / 4);
  float sd = 0.f, sde = 0.f;
#pragma unroll
  for (int it = 0; it < KDIM / 4 / 256; ++it) {
    int k4 = t + it * 256;
    float4 w = wr[k4];
    ushort4 co, c2o;
    wcomp(w.x, co.x, c2o.x, sd, sde);
    wcomp(w.y, co.y, c2o.y, sd, sde);
    wcomp(w.z, co.z, c2o.z, sd, sde);
    wcomp(w.w, co.w, c2o.w, sd, sde);
    cr[k4]  = co;
    c2r[k4] = c2o;
  }
#pragma unroll
  for (int off = 32; off > 0; off >>= 1) {
    sd  += __shfl_down(sd, off);
    sde += __shfl_down(sde, off);
  }
  __shared__ float red[8];
  if ((t & 63) == 0) { red[t >> 6] = sd; red[4 + (t >> 6)] = sde; }
  __syncthreads();
  if (t == 0) {
    sumd[o]  = red[0] + red[1] + red[2] + red[3];
    sumde[o] = red[4] + red[5] + red[6] + red[7];
  }
}

// ---------------- fused dual-GEMM, 3-buffer counted-vmcnt pipeline ----------------
// 512 threads = 8 waves. Waves 0-3: mu = X@C^T; waves 4-7: var = Y@C2^T.
// Each wave: 64 rows x 128 cols of its 128x256 tile (acc[4][8]).
// LDS tile layout (per operand tile): row-pair units of 128B = 8 chunks of 16B;
// chunk c of unit u holds global chunk g = c ^ (u&7), where g = (row&1)*4 + kchunk.
// -> ds_read_b128 fragments land 2 lanes/bank (free); global src stays coalesced.
//
// Schedule: ONE barrier + ONE counted vmcnt(6) per K-tile. With 3 buffers the
// staging target (t+2) has no readers this tile, and every wave's ds_reads of
// that buffer completed before the previous tile-end barrier (the MFMAs consumed
// them), so intra-tile barriers are pure overhead. Compiler inserts fine-grained
// lgkmcnt(N) per MFMA use; waves drift within the tile and hide each other's
// LDS latency. Never drain vmcnt to 0 until the last two tiles.
__global__ __launch_bounds__(512, 2) void gemm_fused_kernel(
    const u16* __restrict__ Xb, const u16* __restrict__ Cb,
    const float* __restrict__ sumd, const float* __restrict__ sumde,
    float* __restrict__ out) {
  __shared__ __attribute__((aligned(128))) char smem[3 * BUF_BYTES];

  const int tid  = threadIdx.x;
  const int lane = tid & 63;
  const int wave = tid >> 6;       // 0..7
  const int grp  = wave >> 2;      // 0 = mu, 1 = var
  const int sub  = wave & 3;
  const int wr   = sub >> 1;       // row half (64 rows each)
  const int wc   = sub & 1;        // col half (128 cols each)
  const int quad = lane >> 4;
  const int r16  = lane & 15;

  // XCD-chunked swizzle: each XCD gets 128 consecutive wgids = 2 N-panels x all M
  const int raw = blockIdx.x;
  const int wg  = (raw & 7) * 128 + (raw >> 3);
  const int n0  = (wg >> 6) * BN;     // 16 N-panels
  const int m0  = (wg & 63) * BM;     // 64 M-panels

  // staging source map (per 8KB round = 128 rows x 64B): thread t -> unit u=t>>3,
  // chunk c=t&7, g=c^(u&7) -> global row 2u+(g>>2), elems (g&3)*8
  const int su    = tid >> 3;
  const int sg    = (tid & 7) ^ (su & 7);
  const int srow  = 2 * su + (sg >> 2);
  const int selem = (sg & 3) * 8;

  const u16* gX = Xb + (size_t)(m0 + srow) * KDIM + selem;
  const u16* gC = Cb + (size_t)(n0 + srow) * KDIM + selem;

#define STAGE_A(sbuf, kt) do {                                              \
    char* _d = smem + (sbuf) * BUF_BYTES + tid * 16;                        \
    const u16* _px = gX + (size_t)(kt) * BK;                                \
    const u16* _pc = gC + (size_t)(kt) * BK;                                \
    async_cp16(_d + LX_OFF, _px);                                           \
    async_cp16(_d + LY_OFF, _px + XY_DELTA);                                \
    async_cp16(_d + LC_OFF, _pc);                                           \
  } while (0)
#define STAGE_B(sbuf, kt) do {                                              \
    char* _d = smem + (sbuf) * BUF_BYTES + tid * 16;                        \
    const u16* _pc = gC + (size_t)(kt) * BK;                                \
    async_cp16(_d + LC_OFF + 8192, _pc + (size_t)128 * KDIM);               \
    async_cp16(_d + LD_OFF,        _pc + CD_DELTA);                         \
    async_cp16(_d + LD_OFF + 8192, _pc + CD_DELTA + (size_t)128 * KDIM);    \
  } while (0)

  // fragment read offsets: row = base + f*16 + r16, kchunk = quad
  // unit u = base/2 + f*8 + (r16>>1); chunk = ((r16&1)*4 + quad) ^ (u&7)
  const int rh    = r16 >> 1;
  const int fbase = rh * 128 + (((((r16 & 1) << 2) + quad) ^ rh) << 4);
  const int aT = (grp ? LY_OFF : LX_OFF) + wr * 4096 + fbase;  // 64-row slice
  const int bT = (grp ? LD_OFF : LC_OFF) + wc * 8192 + fbase;  // 128-col slice

  f32x4 acc[4][8];
#pragma unroll
  for (int i = 0; i < 4; ++i)
#pragma unroll
    for (int j = 0; j < 8; ++j) acc[i][j] = f32x4{0.f, 0.f, 0.f, 0.f};

  // prologue: stage tiles 0 and 1; wait for tile 0 (tile 1's 6 loads stay in flight)
  STAGE_A(0, 0); STAGE_B(0, 0);
  STAGE_A(1, 1); STAGE_B(1, 1);
  asm volatile("s_waitcnt vmcnt(6)" ::: "memory");
  __builtin_amdgcn_s_barrier();

  int rb = 0;  // read buffer = t % 3
  for (int t = 0; t < NT; ++t) {
    const char* base = smem + rb * BUF_BYTES;
    const int sb = rb ? rb - 1 : 2;   // (t+2) % 3
    bf16x8 a[4], b[8];

    // issue all 12 fragment reads + all 6 next-next-tile stages up front
#pragma unroll
    for (int i = 0; i < 4; ++i) a[i] = *(const bf16x8*)(base + aT + i * 1024);
#pragma unroll
    for (int j = 0; j < 8; ++j) b[j] = *(const bf16x8*)(base + bT + j * 1024);
    if (t + 2 < NT) { STAGE_A(sb, t + 2); STAGE_B(sb, t + 2); }
    __builtin_amdgcn_sched_barrier(0);

    __builtin_amdgcn_s_setprio(1);
#pragma unroll
    for (int i = 0; i < 4; ++i)
#pragma unroll
      for (int j = 0; j < 8; ++j)
        acc[i][j] = __builtin_amdgcn_mfma_f32_16x16x32_bf16(a[i], b[j], acc[i][j], 0, 0, 0);
    __builtin_amdgcn_s_setprio(0);

    // tile-end wait: tile t+1's 6 loads done once <=6 (tile t+2's) remain.
    // last two tiles: full drain (also protects epilogue LDS reuse).
    if (t < NT - 2) { asm volatile("s_waitcnt vmcnt(6)" ::: "memory"); }
    else            { asm volatile("s_waitcnt vmcnt(0)" ::: "memory"); }
    __builtin_amdgcn_s_barrier();

    rb = rb + 1 == 3 ? 0 : rb + 1;
  }

  // ---- epilogue ----
  // C/D layout: out col = wc*128 + j*16 + r16, out row = wr*64 + i*16 + quad*4 + reg
  u16* vb = (u16*)smem;
  if (grp) {
    // var waves: round to bf16, park in LDS col-major (stride VSTRIDE)
#pragma unroll
    for (int j = 0; j < 8; ++j) {
      const int cl = wc * 128 + j * 16 + r16;
#pragma unroll
      for (int i = 0; i < 4; ++i) {
        const int rl = wr * 64 + i * 16 + quad * 4;
        f32x4 v = acc[i][j];
        ushort4 p;
        p.x = f2bf(v[0]); p.y = f2bf(v[1]); p.z = f2bf(v[2]); p.w = f2bf(v[3]);
        *(ushort4*)(vb + cl * VSTRIDE + rl) = p;
      }
    }
  }
  __syncthreads();
  if (!grp) {
    const float inv_rt2 = 0.70710678118654752f;
#pragma unroll
    for (int j = 0; j < 8; ++j) {
      const int cl  = wc * 128 + j * 16 + r16;
      const int col = n0 + cl;
      const float sd  = sumd[col];
      const float sde = sumde[col] + EPSF;
#pragma unroll
      for (int i = 0; i < 4; ++i) {
        const int rl   = wr * 64 + i * 16 + quad * 4;
        const int mrow = m0 + rl;
        const ushort4 p = *(const ushort4*)(vb + cl * VSTRIDE + rl);
        f32x4 m4 = acc[i][j];
        const float vv[4] = {bf2f(p.x), bf2f(p.y), bf2f(p.z), bf2f(p.w)};
#pragma unroll
        for (int r = 0; r < 4; ++r) {
          float mu  = m4[r] + sd;
          float var = vv[r] + sde;
          float z = (TM05 - mu) * rsqrtf(var) * inv_rt2;
          out[(size_t)(mrow + r) * ODIM + col] = 0.5f * erfcf(z);
        }
      }
    }
  }
}

// ---------------- launch ----------------
// ws layout (bytes):
//   0         : Cb   (33554432)
//   33554432  : C2b  (33554432)   = Cb + CD_DELTA elems
//   67108864  : sumd (16384)
//   67125248  : sumde(16384)
//   67141632  : Xb   (67108864)
//   134250496 : Yb   (67108864)   = Xb + XY_DELTA elems
extern "C" void kernel_launch(void* const* d_in, const int* in_sizes, int n_in,
                              void* d_out, int out_size, void* d_ws, size_t ws_size,
                              hipStream_t stream) {
  const float* p_x    = (const float*)d_in[0];
  const float* weight = (const float*)d_in[1];
  float* out = (float*)d_out;
  char* ws = (char*)d_ws;

  u16* Cb      = (u16*)(ws);
  float* sumd  = (float*)(ws + 67108864);
  float* sumde = (float*)(ws + 67125248);
  u16* Xb      = (u16*)(ws + 67141632);

  prep_w_kernel<<<ODIM, 256, 0, stream>>>((const float4*)weight, (ushort4*)Cb,
                                          (ushort4*)(ws + 33554432), sumd, sumde);
  prep_x_kernel<<<(MDIM * KDIM / 4) / 256, 256, 0, stream>>>((const float4*)p_x,
                                                             (ushort4*)Xb,
                                                             (ushort4*)(ws + 134250496));
  gemm_fused_kernel<<<dim3((ODIM / BN) * (MDIM / BM)), 512, 0, stream>>>(
      Xb, Cb, sumd, sumde, out);
}

// Round 3
// 774.308 us; speedup vs baseline: 1.2256x; 1.1424x over previous
//
#include <hip/hip_runtime.h>
#include <hip/hip_bf16.h>
#include <math.h>
#include <cstdint>

#define KDIM 4096   // IN_FEATURES
#define ODIM 4096   // OUT_FEATURES
#define MDIM 8192   // N_ROWS
#define EPSF 1e-6f
#define TM05 2047.5f   // threshold(=2048) - 0.5

typedef __bf16 bf16x8 __attribute__((ext_vector_type(8)));
typedef float f32x4 __attribute__((ext_vector_type(4)));
typedef unsigned short u16;

// element deltas inside workspace (buffers laid out contiguously)
#define XY_DELTA (MDIM * KDIM)   // Xb -> Yb   (in u16 elements)
#define CD_DELTA (ODIM * KDIM)   // Cb -> C2b  (in u16 elements)

// ---- m201-template GEMM geometry (single GEMM per kernel) ----
// 256x256 block tile, BK=64, 512 threads = 8 waves (2 M-halves x 4 N-quarters),
// per-wave output 128x64 (acc[8][4]). LDS: 2 buffers x (A 32KB + B 32KB) = 128KB.
// 8 phases per iteration (2 K-tiles); 16 MFMA per phase; 1 half-tile staged per
// phase into dead regions; vmcnt(4) twice per iteration, never 0 mid-loop.
#define NITER (KDIM / 128)   // 32 iterations x 2 K-tiles of 64

__device__ __forceinline__ u16 f2bf(float f) {
  __hip_bfloat16 h = __float2bfloat16(f);
  return __builtin_bit_cast(u16, h);
}
__device__ __forceinline__ float bf2f(u16 b) {
  unsigned int u = ((unsigned int)b) << 16;
  return __builtin_bit_cast(float, u);
}

// async global->LDS direct copy, 16 B per lane (dst must be lane-linear).
__device__ __forceinline__ void async_cp16(void* lds, const void* g) {
  __builtin_amdgcn_global_load_lds(
      (__attribute__((address_space(1))) void*)(uintptr_t)g,
      (__attribute__((address_space(3))) void*)lds, 16, 0, 0);
}

// ---------------- prep: X -> bf16 X, bf16 Y = x*(1-x) ----------------
__global__ void prep_x_kernel(const float4* __restrict__ x4,
                              ushort4* __restrict__ Xb,
                              ushort4* __restrict__ Yb) {
  int i = blockIdx.x * blockDim.x + threadIdx.x;
  float4 v = x4[i];
  ushort4 xo, yo;
  xo.x = f2bf(v.x); xo.y = f2bf(v.y); xo.z = f2bf(v.z); xo.w = f2bf(v.w);
  yo.x = f2bf(v.x * (1.0f - v.x));
  yo.y = f2bf(v.y * (1.0f - v.y));
  yo.z = f2bf(v.z * (1.0f - v.z));
  yo.w = f2bf(v.w * (1.0f - v.w));
  Xb[i] = xo;
  Yb[i] = yo;
}

// ---------------- prep: W -> bf16 C=2*sig(w)-1, bf16 C2=C*C, sums ----------------
__device__ __forceinline__ void wcomp(float w, u16& cb, u16& c2b, float& sd, float& sde) {
  float pw = 1.0f / (1.0f + __expf(-w));
  float c  = 2.0f * pw - 1.0f;
  float d  = 1.0f - pw;
  cb  = f2bf(c);
  c2b = f2bf(c * c);
  sd  += d;
  sde += d * pw;
}

__global__ void prep_w_kernel(const float4* __restrict__ w4,
                              ushort4* __restrict__ Cb,
                              ushort4* __restrict__ C2b,
                              float* __restrict__ sumd,
                              float* __restrict__ sumde) {
  const int o = blockIdx.x;
  const int t = threadIdx.x;
  const float4* wr = w4 + (size_t)o * (KDIM / 4);
  ushort4* cr  = Cb  + (size_t)o * (KDIM / 4);
  ushort4* c2r = C2b + (size_t)o * (KDIM / 4);
  float sd = 0.f, sde = 0.f;
#pragma unroll
  for (int it = 0; it < KDIM / 4 / 256; ++it) {
    int k4 = t + it * 256;
    float4 w = wr[k4];
    ushort4 co, c2o;
    wcomp(w.x, co.x, c2o.x, sd, sde);
    wcomp(w.y, co.y, c2o.y, sd, sde);
    wcomp(w.z, co.z, c2o.z, sd, sde);
    wcomp(w.w, co.w, c2o.w, sd, sde);
    cr[k4]  = co;
    c2r[k4] = c2o;
  }
#pragma unroll
  for (int off = 32; off > 0; off >>= 1) {
    sd  += __shfl_down(sd, off);
    sde += __shfl_down(sde, off);
  }
  __shared__ float red[8];
  if ((t & 63) == 0) { red[t >> 6] = sd; red[4 + (t >> 6)] = sde; }
  __syncthreads();
  if (t == 0) {
    sumd[o]  = red[0] + red[1] + red[2] + red[3];
    sumde[o] = red[4] + red[5] + red[6] + red[7];
  }
}

// ---------------- 256^2 8-phase GEMM (m201 template port) ----------------
// LDS swizzle: row of 64 bf16 = 8 granules of 16B; stored granule = g ^ (row&7)
// -> ds_read_b128 fragments land 2 lanes/bank (free, m136); staging pre-swizzles
// the GLOBAL source granule so LDS dst stays lane-linear (global_load_lds req).
//
// Dead-region staging map per iteration s (buf0 = tile 2s, buf1 = tile 2s+1):
//   gp0: buf1.A0 <- tile 2s+1   (buf1.A dead since prev gp7 barrier)
//   gp1: buf1.A1 <- tile 2s+1
//   gp2: buf0.B0 <- tile 2s+2   (buf0.B dead after gp0: B-frags read once, held)
//   gp3: buf0.B1 <- tile 2s+2   + vmcnt(4) (retires gp0/gp1 -> buf1.A ready)
//   gp4: buf0.A0 <- tile 2s+2   (buf0.A dead after gp3)
//   gp5: buf0.A1 <- tile 2s+2
//   gp6: buf1.B0 <- tile 2s+3   (buf1.B dead after gp4)
//   gp7: buf1.B1 <- tile 2s+3   + vmcnt(4) (retires gp2..gp5 -> buf0 ready)

#define STG_H(bb, isB, half, srcB, tt) do {                                    \
    char* _d = smem + (bb) * 65536 + (isB) * 32768 + (half) * 16384 + tid * 16;\
    const u16* _s = (srcB) + (size_t)((half) * 128) * KDIM + (size_t)(tt) * 64;\
    async_cp16(_d, _s);                                                        \
    async_cp16(_d + 8192, _s + (size_t)64 * KDIM);                             \
  } while (0)

#define PHASE(bb, p, STG, VM) {                                                \
    const char* Ab = smem + (bb) * 65536;                                      \
    const char* Bb = Ab + 32768;                                               \
    bf16x8 a0k0 = *(const bf16x8*)(Ab + arow + ((p) * 2 + 0) * 2048 + g0);     \
    bf16x8 a0k1 = *(const bf16x8*)(Ab + arow + ((p) * 2 + 0) * 2048 + g1);     \
    bf16x8 a1k0 = *(const bf16x8*)(Ab + arow + ((p) * 2 + 1) * 2048 + g0);     \
    bf16x8 a1k1 = *(const bf16x8*)(Ab + arow + ((p) * 2 + 1) * 2048 + g1);     \
    if ((p) == 0) {                                                            \
      _Pragma("unroll") for (int j = 0; j < 4; ++j) {                          \
        b0[j] = *(const bf16x8*)(Bb + brow + j * 2048 + g0);                   \
        b1[j] = *(const bf16x8*)(Bb + brow + j * 2048 + g1);                   \
      }                                                                        \
    }                                                                          \
    STG;                                                                       \
    __builtin_amdgcn_s_barrier();                                              \
    asm volatile("s_waitcnt lgkmcnt(0)" ::: "memory");                         \
    __builtin_amdgcn_sched_barrier(0);                                         \
    __builtin_amdgcn_s_setprio(1);                                             \
    _Pragma("unroll") for (int j = 0; j < 4; ++j)                              \
      acc[(p)*2+0][j] = __builtin_amdgcn_mfma_f32_16x16x32_bf16(a0k0, b0[j], acc[(p)*2+0][j], 0, 0, 0); \
    _Pragma("unroll") for (int j = 0; j < 4; ++j)                              \
      acc[(p)*2+1][j] = __builtin_amdgcn_mfma_f32_16x16x32_bf16(a1k0, b0[j], acc[(p)*2+1][j], 0, 0, 0); \
    _Pragma("unroll") for (int j = 0; j < 4; ++j)                              \
      acc[(p)*2+0][j] = __builtin_amdgcn_mfma_f32_16x16x32_bf16(a0k1, b1[j], acc[(p)*2+0][j], 0, 0, 0); \
    _Pragma("unroll") for (int j = 0; j < 4; ++j)                              \
      acc[(p)*2+1][j] = __builtin_amdgcn_mfma_f32_16x16x32_bf16(a1k1, b1[j], acc[(p)*2+1][j], 0, 0, 0); \
    __builtin_amdgcn_s_setprio(0);                                             \
    VM;                                                                        \
    __builtin_amdgcn_s_barrier();                                              \
  }

// PASS 0: var GEMM (Y @ C2^T), writes raw f32 var into out.
// PASS 1: mu GEMM (X @ C^T), reads var from out, applies erfc epilogue in place.
template <int PASS>
__global__ __launch_bounds__(512, 2) void gemm_pass_kernel(
    const u16* __restrict__ Ag, const u16* __restrict__ Bg,
    const float* __restrict__ sumd, const float* __restrict__ sumde,
    float* __restrict__ out) {
  __shared__ __attribute__((aligned(128))) char smem[2 * 65536];

  const int tid  = threadIdx.x;
  const int lane = tid & 63;
  const int wave = tid >> 6;       // 0..7
  const int wr   = wave >> 2;      // M half (128 rows)
  const int wc   = wave & 3;       // N quarter (64 cols)
  const int quad = lane >> 4;
  const int r16  = lane & 15;

  // bijective XCD chunking: 512 wgs = 8 XCDs x 64; each XCD streams 2 N-panels
  const int raw = blockIdx.x;
  const int wg  = (raw & 7) * 64 + (raw >> 3);
  const int n0  = (wg >> 5) * 256;   // 16 N-panels
  const int m0  = (wg & 31) * 256;   // 32 M-panels

  // staging source map (8KB round = 64 rows x 128B): thread t -> row t>>3,
  // dst granule t&7, global granule (t&7)^(row&7)
  const int srow = tid >> 3;
  const int scol = ((tid & 7) ^ (srow & 7)) * 8;
  const u16* gA = Ag + (size_t)(m0 + srow) * KDIM + scol;
  const u16* gB = Bg + (size_t)(n0 + srow) * KDIM + scol;

  // fragment read offsets: row = base + r16 (mod 8 == r16&7), granule ks*4+quad
  const int r7   = r16 & 7;
  const int g0   = (quad ^ r7) * 16;
  const int g1   = ((4 | quad) ^ r7) * 16;
  const int arow = (wr * 128 + r16) * 128;
  const int brow = (wc * 64 + r16) * 128;

  f32x4 acc[8][4];
#pragma unroll
  for (int i = 0; i < 8; ++i)
#pragma unroll
    for (int j = 0; j < 4; ++j) acc[i][j] = f32x4{0.f, 0.f, 0.f, 0.f};

  bf16x8 b0[4], b1[4];

  // prologue: buf0 <- tile0 (A+B), buf1.B <- tile1; vmcnt(4) retires buf0's 8
  STG_H(0, 0, 0, gA, 0); STG_H(0, 0, 1, gA, 0);
  STG_H(0, 1, 0, gB, 0); STG_H(0, 1, 1, gB, 0);
  STG_H(1, 1, 0, gB, 1); STG_H(1, 1, 1, gB, 1);
  asm volatile("s_waitcnt vmcnt(4)" ::: "memory");
  __builtin_amdgcn_s_barrier();

  for (int s = 0; s < NITER; ++s) {
    const bool nlast = (s + 1 < NITER);
    const int t1 = 2 * s + 1, t2 = 2 * s + 2, t3 = 2 * s + 3;

    PHASE(0, 0, STG_H(1, 0, 0, gA, t1), )
    PHASE(0, 1, STG_H(1, 0, 1, gA, t1), )
    PHASE(0, 2, if (nlast) STG_H(0, 1, 0, gB, t2), )
    PHASE(0, 3, if (nlast) STG_H(0, 1, 1, gB, t2),
          if (nlast) { asm volatile("s_waitcnt vmcnt(4)" ::: "memory"); }
          else       { asm volatile("s_waitcnt vmcnt(0)" ::: "memory"); })
    PHASE(1, 0, if (nlast) STG_H(0, 0, 0, gA, t2), )
    PHASE(1, 1, if (nlast) STG_H(0, 0, 1, gA, t2), )
    PHASE(1, 2, if (nlast) STG_H(1, 1, 0, gB, t3), )
    PHASE(1, 3, if (nlast) STG_H(1, 1, 1, gB, t3),
          if (nlast) { asm volatile("s_waitcnt vmcnt(4)" ::: "memory"); }
          else       { asm volatile("s_waitcnt vmcnt(0)" ::: "memory"); })
  }

  // ---- epilogue ----
  // C/D layout: out col = n0 + wc*64 + j*16 + r16, row = m0 + wr*128 + i*16 + quad*4 + r
  if (PASS == 0) {
#pragma unroll
    for (int j = 0; j < 4; ++j) {
      const int col = n0 + wc * 64 + j * 16 + r16;
#pragma unroll
      for (int i = 0; i < 8; ++i) {
        const int row = m0 + wr * 128 + i * 16 + quad * 4;
        f32x4 v = acc[i][j];
#pragma unroll
        for (int r = 0; r < 4; ++r) out[(size_t)(row + r) * ODIM + col] = v[r];
      }
    }
  } else {
    const float inv_rt2 = 0.70710678118654752f;
#pragma unroll
    for (int j = 0; j < 4; ++j) {
      const int col = n0 + wc * 64 + j * 16 + r16;
      const float sd  = sumd[col];
      const float sde = sumde[col] + EPSF;
#pragma unroll
      for (int i = 0; i < 8; ++i) {
        const int row = m0 + wr * 128 + i * 16 + quad * 4;
        f32x4 m4 = acc[i][j];
#pragma unroll
        for (int r = 0; r < 4; ++r) {
          float var = out[(size_t)(row + r) * ODIM + col] + sde;
          float mu  = m4[r] + sd;
          float z = (TM05 - mu) * rsqrtf(var) * inv_rt2;
          out[(size_t)(row + r) * ODIM + col] = 0.5f * erfcf(z);
        }
      }
    }
  }
}

// ---------------- launch ----------------
// ws layout (bytes):
//   0         : Cb   (33554432)
//   33554432  : C2b  (33554432)   = Cb + CD_DELTA elems
//   67108864  : sumd (16384)
//   67125248  : sumde(16384)
//   67141632  : Xb   (67108864)
//   134250496 : Yb   (67108864)   = Xb + XY_DELTA elems
extern "C" void kernel_launch(void* const* d_in, const int* in_sizes, int n_in,
                              void* d_out, int out_size, void* d_ws, size_t ws_size,
                              hipStream_t stream) {
  const float* p_x    = (const float*)d_in[0];
  const float* weight = (const float*)d_in[1];
  float* out = (float*)d_out;
  char* ws = (char*)d_ws;

  u16* Cb      = (u16*)(ws);
  u16* C2b     = (u16*)(ws + 33554432);
  float* sumd  = (float*)(ws + 67108864);
  float* sumde = (float*)(ws + 67125248);
  u16* Xb      = (u16*)(ws + 67141632);
  u16* Yb      = (u16*)(ws + 134250496);

  prep_w_kernel<<<ODIM, 256, 0, stream>>>((const float4*)weight, (ushort4*)Cb,
                                          (ushort4*)C2b, sumd, sumde);
  prep_x_kernel<<<(MDIM * KDIM / 4) / 256, 256, 0, stream>>>((const float4*)p_x,
                                                             (ushort4*)Xb,
                                                             (ushort4*)Yb);
  const int nwg = (MDIM / 256) * (ODIM / 256);  // 512
  gemm_pass_kernel<0><<<nwg, 512, 0, stream>>>(Yb, C2b, sumd, sumde, out);
  gemm_pass_kernel<1><<<nwg, 512, 0, stream>>>(Xb, Cb, sumd, sumde, out);
}